// Round 6
// baseline (303.540 us; speedup 1.0000x reference)
//
#include <hip/hip_runtime.h>
#include <cmath>

#define T_SEQ 1024
#define EMB   1024
#define NH    16
#define HD    64
#define NB    4
#define BQ    64
#define BK    64

// softmax computed in log2 domain: exp(x) == exp2(x * log2e)
#define QSCALE 0.18033688011112042f   /* 0.125 * log2(e) */
#define BIAS2  -1.44269504e9f         /* -1e9 * log2(e) */

using frag8   = __attribute__((ext_vector_type(8))) short;
using f32x4   = __attribute__((ext_vector_type(4))) float;
using short4v = __attribute__((ext_vector_type(4))) short;
using short8v = __attribute__((ext_vector_type(8))) short;

__device__ inline short f2bf(float f) {               // RNE
    union { float f; unsigned u; } x; x.f = f;
    unsigned r = (x.u + 0x7FFFu + ((x.u >> 16) & 1u)) >> 16;
    return (short)r;
}
__device__ inline short f2bf_rhu(float f) {           // round-half-up, 2 ops
    union { float f; unsigned u; } x; x.f = f;
    return (short)((x.u + 0x8000u) >> 16);
}
__device__ inline float bf2f(unsigned short u) {
    union { unsigned u; float f; } x; x.u = ((unsigned)u) << 16;
    return x.f;
}

__device__ inline void glds16(const short* g, short* l) {
    __builtin_amdgcn_global_load_lds(
        (const __attribute__((address_space(1))) void*)g,
        (__attribute__((address_space(3))) void*)l, 16, 0, 0);
}

// ---------------------------------------------------------------------------
// fp32 -> bf16 converts (3 inputs + 4 weights), all coalesced.
// ---------------------------------------------------------------------------
struct ConvArgs { const float* src[7]; short* dst[7]; int n8[7]; };

__global__ __launch_bounds__(256) void convert_bf16(ConvArgs a) {
    const int y = blockIdx.y;
    const int t = blockIdx.x * 256 + threadIdx.x;
    if (t >= a.n8[y]) return;
    const float4* s = (const float4*)a.src[y];
    const float4 v0 = s[t * 2], v1 = s[t * 2 + 1];
    short8v o;
    o[0] = f2bf(v0.x); o[1] = f2bf(v0.y); o[2] = f2bf(v0.z); o[3] = f2bf(v0.w);
    o[4] = f2bf(v1.x); o[5] = f2bf(v1.y); o[6] = f2bf(v1.z); o[7] = f2bf(v1.w);
    *(short8v*)&a.dst[y][t * 8] = o;
}

// ---------------------------------------------------------------------------
// Mask int32 -> bf16 additive bias, fragment-tile layout
// idx = ((b*64+rt16)*64+c16)*256 + (col%16)*16 + (row%16).
// One wave per 16x16 tile; coalesced int4 row reads, in-register transpose.
// ---------------------------------------------------------------------------
__global__ __launch_bounds__(256) void convert_mask(
    const int* __restrict__ mask, short* __restrict__ dst)
{
    const int wave = threadIdx.x >> 6, lane = threadIdx.x & 63;
    const int tile = blockIdx.x * 4 + wave;          // (b*64+rt16)*64+c16
    const int bb   = tile >> 12;
    const int rt16 = (tile >> 6) & 63;
    const int c16  = tile & 63;
    const int row_in = lane >> 2;
    const int col4   = (lane & 3) * 4;
    const int4 mv = *(const int4*)&mask[((size_t)bb * T_SEQ + rt16 * 16 + row_in) * T_SEQ
                                        + c16 * 16 + col4];
    const short BB = f2bf(BIAS2);
    short* o = dst + (size_t)tile * 256 + row_in;
    o[(col4 + 0) * 16] = mv.x ? (short)0 : BB;
    o[(col4 + 1) * 16] = mv.y ? (short)0 : BB;
    o[(col4 + 2) * 16] = mv.z ? (short)0 : BB;
    o[(col4 + 3) * 16] = mv.w ? (short)0 : BB;
}

// ---------------------------------------------------------------------------
// bf16 MFMA GEMM core (m97 structure): C = (A(MxK) @ W(NxK)^T + bias) * scale
// MODE 0: fp32 C-order out  [m16][n16][rr][quad][lm]   (LayerNorm-consumed)
// MODE 1: bf16 C-order out  [bh][t16][d16][rr][quad][lm]  (Q and K)
// MODE 2: bf16 V^T frag out [bh][kt64][kh][dc][kq][dlm][8]
// All MODE epilogue stores are wave-coalesced.
// ---------------------------------------------------------------------------
struct GemmB { const short* A; const short* W; const float* bias; short* out; float scale; };
struct QkvArgs { GemmB g[3]; };

template <int MODE>
__device__ inline void gemm_core(const short* __restrict__ A,
                                 const short* __restrict__ W,
                                 const float* __restrict__ bias,
                                 float scale,
                                 short* __restrict__ outS,
                                 float* __restrict__ outF,
                                 int m0, int n0)
{
    __shared__ short As[128 * 32];
    __shared__ short Bs[128 * 32];

    const int tid  = threadIdx.x;
    const int wave = tid >> 6;
    const int lane = tid & 63;
    const int quad = lane >> 4;
    const int lm   = lane & 15;
    const int wr   = wave >> 1;
    const int wc   = wave & 1;
    const int K    = EMB;

    const int G0 = wave * 64 + lane, G1 = G0 + 256;
    const short* aSrc0 = A + (size_t)(m0 + (G0 >> 2)) * K + (G0 & 3) * 8;
    const short* aSrc1 = A + (size_t)(m0 + (G1 >> 2)) * K + (G1 & 3) * 8;
    const short* bSrc0 = W + (size_t)(n0 + (G0 >> 2)) * K + (G0 & 3) * 8;
    const short* bSrc1 = W + (size_t)(n0 + (G1 >> 2)) * K + (G1 & 3) * 8;
    short* aDst0 = As + wave * 512;
    short* aDst1 = As + 2048 + wave * 512;
    short* bDst0 = Bs + wave * 512;
    short* bDst1 = Bs + 2048 + wave * 512;

    f32x4 acc[4][4];
#pragma unroll
    for (int i = 0; i < 4; ++i)
#pragma unroll
        for (int j = 0; j < 4; ++j) acc[i][j] = (f32x4){0.f, 0.f, 0.f, 0.f};

    for (int kk = 0; kk < K; kk += 32) {
        __syncthreads();
        glds16(aSrc0 + kk, aDst0);
        glds16(aSrc1 + kk, aDst1);
        glds16(bSrc0 + kk, bDst0);
        glds16(bSrc1 + kk, bDst1);
        __syncthreads();

        frag8 aF[4], bF[4];
#pragma unroll
        for (int i = 0; i < 4; ++i)
            aF[i] = *(const frag8*)&As[(wr * 64 + i * 16 + lm) * 32 + quad * 8];
#pragma unroll
        for (int j = 0; j < 4; ++j)
            bF[j] = *(const frag8*)&Bs[(wc * 64 + j * 16 + lm) * 32 + quad * 8];
#pragma unroll
        for (int i = 0; i < 4; ++i)
#pragma unroll
            for (int j = 0; j < 4; ++j)
                acc[i][j] = __builtin_amdgcn_mfma_f32_16x16x32_bf16(
                    aF[i], bF[j], acc[i][j], 0, 0, 0);
    }

#pragma unroll
    for (int i = 0; i < 4; ++i)
#pragma unroll
        for (int j = 0; j < 4; ++j) {
            const int n = n0 + wc * 64 + j * 16 + lm;
            const float bv = bias[n];
#pragma unroll
            for (int rr = 0; rr < 4; ++rr) {
                const int m = m0 + wr * 64 + i * 16 + quad * 4 + rr;
                const float val = (acc[i][j][rr] + bv) * scale;
                if (MODE == 0) {
                    // fp32 C-order: [m16][n16][rr][quad][lm] — coalesced
                    outF[((size_t)(m >> 4) * 64 + (n >> 4)) * 256 +
                         rr * 64 + quad * 16 + lm] = val;
                } else {
                    const int bb = m >> 10, tt = m & 1023;
                    const int h = n >> 6,  d  = n & 63;
                    const size_t bh = (size_t)bb * NH + h;
                    if (MODE == 1) {
                        // bf16 C-order: [bh][t16][d16][rr][quad][lm] — coalesced
                        outS[((bh * 64 + (tt >> 4)) * 4 + (d >> 4)) * 256 +
                             rr * 64 + quad * 16 + lm] = f2bf(val);
                    } else {
                        // V^T B-frag order
                        outS[((((bh * 16 + (tt >> 6)) * 2 + ((tt >> 5) & 1)) * 4 +
                              (d >> 4)) * 4 + ((tt >> 3) & 3)) * 128 +
                             (d & 15) * 8 + (tt & 7)] = f2bf(val);
                    }
                }
            }
        }
}

// XCD-colocating swizzle: flat id -> (a = XCD slot, n', pair(m',z')).
// All 8 n-blocks of one (m,z) pair share `a` => A-tile fetched once per XCD.
__global__ __launch_bounds__(256) void gemm_qkv(QkvArgs args) {
    const int id = blockIdx.x + 8 * blockIdx.y + 256 * blockIdx.z;  // 0..767
    const int a  = id & 7;
    const int k2 = id >> 3;          // 0..95
    const int nb = k2 & 7;
    const int c  = k2 >> 3;          // 0..11
    const int pair = a * 12 + c;     // 0..95
    const int mb = pair & 31;
    const int zb = pair >> 5;        // 0..2
    const GemmB g = args.g[zb];
    if (zb < 2) gemm_core<1>(g.A, g.W, g.bias, g.scale, g.out, nullptr, mb * 128, nb * 128);
    else        gemm_core<2>(g.A, g.W, g.bias, g.scale, g.out, nullptr, mb * 128, nb * 128);
}

__global__ __launch_bounds__(256) void gemm_wo(const short* __restrict__ A,
                                               const short* __restrict__ W,
                                               const float* __restrict__ bias,
                                               float* __restrict__ out) {
    const int id = blockIdx.x + 8 * blockIdx.y;   // 0..255
    const int a  = id & 7;
    const int k2 = id >> 3;          // 0..31
    const int nb = k2 & 7;
    const int c  = k2 >> 3;          // 0..3
    const int mb = a * 4 + c;        // 0..31
    gemm_core<0>(A, W, bias, 1.0f, nullptr, out, mb * 128, nb * 128);
}

// ---------------------------------------------------------------------------
// Flash attention: fragment-resident K/V (no staging barriers),
// fixed-max log2-domain softmax, deferred l reduction.
// Q/K in C-order layout, V in B-frag layout, mask in frag tiles.
// ---------------------------------------------------------------------------
__global__ __launch_bounds__(256, 4) void flash_attn_mfma(
    const short* __restrict__ qf_, const short* __restrict__ kf_,
    const short* __restrict__ vf_, const short* __restrict__ mf_,
    short* __restrict__ out)
{
    __shared__ short Pl[4][2][16][72];   // per-wave, parity double-buffered

    const int tid  = threadIdx.x;
    const int wave = tid >> 6;
    const int lane = tid & 63;
    const int quad = lane >> 4;
    const int lm   = lane & 15;

    const int b  = blockIdx.z, h = blockIdx.y;
    const int q0 = blockIdx.x * BQ;
    const size_t bh = (size_t)b * NH + h;

    // C-order fragment offset for A/B operands (token=lm, d=quad*8+j)
    const int foff = (quad >> 1) * 256 + (lm & 3) * 64 + (lm >> 2) * 16 + (quad & 1) * 8;

    // Q fragments (coalesced 1KB wave loads)
    const short* qb_ = qf_ + (bh * 64 + (q0 >> 4) + wave) * 1024;
    const frag8 qfa = *(const frag8*)&qb_[foff];
    const frag8 qfb = *(const frag8*)&qb_[foff + 512];

    // mask fragment base for this wave's 16 q-rows
    const short* mrow = mf_ + ((size_t)b * 64 + (q0 >> 4) + wave) * (64 * 256)
                        + lm * 16 + quad * 4;

    f32x4 of[4];
#pragma unroll
    for (int dc = 0; dc < 4; ++dc) of[dc] = (f32x4){0.f, 0.f, 0.f, 0.f};
    float lsum[4] = {0.f, 0.f, 0.f, 0.f};

    for (int kt2 = 0; kt2 < T_SEQ / BK; ++kt2) {
        const int pp = kt2 & 1;

        // V fragments: 8 coalesced dwordx4
        frag8 vf[2][4];
        const short* vbase = vf_ + (bh * 16 + kt2) * 4096;
#pragma unroll
        for (int kh2 = 0; kh2 < 2; ++kh2)
#pragma unroll
            for (int dc = 0; dc < 4; ++dc)
                vf[kh2][dc] = *(const frag8*)
                    &vbase[((kh2 * 4 + dc) * 4 + quad) * 128 + lm * 8];

        // mask bias: 4 coalesced dwordx2
        short4v mb[4];
#pragma unroll
        for (int kc = 0; kc < 4; ++kc)
            mb[kc] = *(const short4v*)&mrow[(kt2 * 4 + kc) * 256];

        // S = Q'K^T + maskbias (acc-init); K frags coalesced dwordx4
        f32x4 s[4];
#pragma unroll
        for (int kc = 0; kc < 4; ++kc) {
            const short* kbase = kf_ + (bh * 64 + kt2 * 4 + kc) * 1024;
            const frag8 kfa = *(const frag8*)&kbase[foff];
            const frag8 kfb = *(const frag8*)&kbase[foff + 512];
            f32x4 a = (f32x4){ bf2f((unsigned short)mb[kc][0]),
                               bf2f((unsigned short)mb[kc][1]),
                               bf2f((unsigned short)mb[kc][2]),
                               bf2f((unsigned short)mb[kc][3]) };
            a = __builtin_amdgcn_mfma_f32_16x16x32_bf16(qfa, kfa, a, 0, 0, 0);
            a = __builtin_amdgcn_mfma_f32_16x16x32_bf16(qfb, kfb, a, 0, 0, 0);
            s[kc] = a;
        }

        // fixed-max softmax: p = exp2(s); deferred row-sum
#pragma unroll
        for (int kc = 0; kc < 4; ++kc)
#pragma unroll
            for (int r = 0; r < 4; ++r) {
                const float p = exp2f(s[kc][r]);
                lsum[r] += p;
                Pl[wave][pp][quad * 4 + r][kc * 16 + lm] = f2bf_rhu(p);
            }

        // P fragments (C->A layout via per-wave LDS) + PV
        const frag8 pfa = *(const frag8*)&Pl[wave][pp][lm][quad * 8];
        const frag8 pfb = *(const frag8*)&Pl[wave][pp][lm][32 + quad * 8];
#pragma unroll
        for (int dc = 0; dc < 4; ++dc) {
            of[dc] = __builtin_amdgcn_mfma_f32_16x16x32_bf16(pfa, vf[0][dc], of[dc], 0, 0, 0);
            of[dc] = __builtin_amdgcn_mfma_f32_16x16x32_bf16(pfb, vf[1][dc], of[dc], 0, 0, 0);
        }
    }

    // final l reduction over the 16-lane lm group
#pragma unroll
    for (int r = 0; r < 4; ++r) {
        lsum[r] += __shfl_xor(lsum[r], 1);
        lsum[r] += __shfl_xor(lsum[r], 2);
        lsum[r] += __shfl_xor(lsum[r], 4);
        lsum[r] += __shfl_xor(lsum[r], 8);
    }
    float inv[4];
#pragma unroll
    for (int r = 0; r < 4; ++r) inv[r] = 1.0f / lsum[r];

    short* ob = out + ((size_t)b * T_SEQ + q0 + wave * 16) * EMB + h * HD;
#pragma unroll
    for (int dc = 0; dc < 4; ++dc)
#pragma unroll
        for (int r = 0; r < 4; ++r)
            ob[(size_t)(quad * 4 + r) * EMB + dc * 16 + lm] = f2bf(of[dc][r] * inv[r]);
}

// ---------------------------------------------------------------------------
// LayerNorm over last dim (1024); input in fp32 C-order, output row-major.
// ---------------------------------------------------------------------------
__global__ __launch_bounds__(256) void layernorm_k(
    const float* __restrict__ x, const float* __restrict__ gamma,
    const float* __restrict__ beta, float* __restrict__ out)
{
    __shared__ float ws1[4], ws2[4];
    const int tid = threadIdx.x;
    const int row = blockIdx.x;
    const int m16 = row >> 4, rr = row & 3, qd = (row >> 2) & 3;

    const float4 v = *(const float4*)&x[((size_t)m16 * 64 + (tid >> 2)) * 256 +
                                        rr * 64 + qd * 16 + (tid & 3) * 4];
    float s  = v.x + v.y + v.z + v.w;
    float ss = v.x * v.x + v.y * v.y + v.z * v.z + v.w * v.w;
#pragma unroll
    for (int off = 32; off > 0; off >>= 1) {
        s  += __shfl_down(s, off);
        ss += __shfl_down(ss, off);
    }
    if ((tid & 63) == 0) { ws1[tid >> 6] = s; ws2[tid >> 6] = ss; }
    __syncthreads();
    if (tid == 0) {
        const float a = ws1[0] + ws1[1] + ws1[2] + ws1[3];
        const float bsum = ws2[0] + ws2[1] + ws2[2] + ws2[3];
        const float mu = a * (1.0f / EMB);
        const float var = bsum * (1.0f / EMB) - mu * mu;
        ws1[0] = mu;
        ws2[0] = rsqrtf(var + 1e-5f);
    }
    __syncthreads();
    const float mu = ws1[0], rstd = ws2[0];

    const float4 g = *(const float4*)&gamma[tid * 4];
    const float4 bt = *(const float4*)&beta[tid * 4];
    float4 r;
    r.x = (v.x - mu) * rstd * g.x + bt.x;
    r.y = (v.y - mu) * rstd * g.y + bt.y;
    r.z = (v.z - mu) * rstd * g.z + bt.z;
    r.w = (v.w - mu) * rstd * g.w + bt.w;
    *(float4*)&out[(size_t)row * EMB + tid * 4] = r;
}

// ---------------------------------------------------------------------------
extern "C" void kernel_launch(void* const* d_in, const int* in_sizes, int n_in,
                              void* d_out, int out_size, void* d_ws, size_t ws_size,
                              hipStream_t stream) {
    const float* query = (const float*)d_in[0];
    const float* key_i = (const float*)d_in[1];
    const float* value = (const float*)d_in[2];
    const int*   mask  = (const int*)d_in[3];
    const float* Wq = (const float*)d_in[4];
    const float* bq = (const float*)d_in[5];
    const float* Wk = (const float*)d_in[6];
    const float* bk = (const float*)d_in[7];
    const float* Wv = (const float*)d_in[8];
    const float* bv = (const float*)d_in[9];
    const float* Wo = (const float*)d_in[10];
    const float* bo = (const float*)d_in[11];
    const float* gamma = (const float*)d_in[12];
    const float* beta  = (const float*)d_in[13];

    const size_t SZ = (size_t)NB * T_SEQ * EMB;   // 4.19M elements
    const size_t WZ = (size_t)EMB * EMB;          // 1.05M elements
    short* sws = (short*)d_ws;
    short* q_bf  = sws;               // dead after gemm_qkv; attnb overlays
    short* k_bf  = sws + SZ;          // dead after gemm_qkv; projb overlays
    short* v_bf  = sws + 2 * SZ;
    short* w_bf  = sws + 3 * SZ;      // Wq,Wk,Wv,Wo bf16
    short* qh    = sws + 4 * SZ;      // Q C-order layout
    short* kh    = sws + 5 * SZ;      // K C-order layout
    short* vh    = sws + 6 * SZ;      // V^T frag layout
    short* maskb = sws + 7 * SZ;      // bf16 bias, fragment tiles
    short* attnb = q_bf;
    float* projb = (float*)(sws + SZ);

    // 1a. bulk converts (inputs + weights)
    ConvArgs ca;
    ca.src[0] = query; ca.dst[0] = q_bf;          ca.n8[0] = (int)(SZ / 8);
    ca.src[1] = key_i; ca.dst[1] = k_bf;          ca.n8[1] = (int)(SZ / 8);
    ca.src[2] = value; ca.dst[2] = v_bf;          ca.n8[2] = (int)(SZ / 8);
    ca.src[3] = Wq;    ca.dst[3] = w_bf;          ca.n8[3] = (int)(WZ / 8);
    ca.src[4] = Wk;    ca.dst[4] = w_bf + WZ;     ca.n8[4] = (int)(WZ / 8);
    ca.src[5] = Wv;    ca.dst[5] = w_bf + 2 * WZ; ca.n8[5] = (int)(WZ / 8);
    ca.src[6] = Wo;    ca.dst[6] = w_bf + 3 * WZ; ca.n8[6] = (int)(WZ / 8);
    convert_bf16<<<dim3((SZ / 8 + 255) / 256, 7), 256, 0, stream>>>(ca);

    // 1b. mask -> frag-tile bias (coalesced)
    convert_mask<<<dim3(NB * 64 * 64 / 4), 256, 0, stream>>>(mask, maskb);

    // 2. QKV projections; Q pre-scaled by 0.125*log2e; frag-layout outputs
    QkvArgs qa;
    qa.g[0] = { q_bf, w_bf,          bq, qh, QSCALE };
    qa.g[1] = { k_bf, w_bf + WZ,     bk, kh, 1.0f };
    qa.g[2] = { v_bf, w_bf + 2 * WZ, bv, vh, 1.0f };
    gemm_qkv<<<dim3(EMB / 128, NB * T_SEQ / 128, 3), 256, 0, stream>>>(qa);

    // 3. flash attention (barrier-free, fragment-resident)
    flash_attn_mfma<<<dim3(T_SEQ / BQ, NH, NB), 256, 0, stream>>>(qh, kh, vh, maskb, attnb);

    // 4. output projection (fp32 C-order out)
    gemm_wo<<<dim3(EMB / 128, NB * T_SEQ / 128), 256, 0, stream>>>(
        attnb, w_bf + 3 * WZ, bo, projb);

    // 5. layernorm (reads C-order, writes row-major)
    layernorm_k<<<dim3(NB * T_SEQ), 256, 0, stream>>>(projb, gamma, beta, (float*)d_out);
}

// Round 7
// 266.549 us; speedup vs baseline: 1.1388x; 1.1388x over previous
//
#include <hip/hip_runtime.h>
#include <cmath>

#define T_SEQ 1024
#define EMB   1024
#define NH    16
#define HD    64
#define NB    4
#define BQ    64
#define BK    64

// softmax computed in log2 domain: exp(x) == exp2(x * log2e)
#define QSCALE 0.18033688011112042f   /* 0.125 * log2(e) */
#define BIAS2  -1.44269504e9f         /* -1e9 * log2(e) */

using frag8   = __attribute__((ext_vector_type(8))) short;
using f32x4   = __attribute__((ext_vector_type(4))) float;
using short4v = __attribute__((ext_vector_type(4))) short;
using short8v = __attribute__((ext_vector_type(8))) short;

__device__ inline short f2bf(float f) {               // RNE
    union { float f; unsigned u; } x; x.f = f;
    unsigned r = (x.u + 0x7FFFu + ((x.u >> 16) & 1u)) >> 16;
    return (short)r;
}
__device__ inline short f2bf_rhu(float f) {           // round-half-up, 2 ops
    union { float f; unsigned u; } x; x.f = f;
    return (short)((x.u + 0x8000u) >> 16);
}
__device__ inline float bf2f(unsigned short u) {
    union { unsigned u; float f; } x; x.u = ((unsigned)u) << 16;
    return x.f;
}

__device__ inline void glds16(const short* g, short* l) {
    __builtin_amdgcn_global_load_lds(
        (const __attribute__((address_space(1))) void*)g,
        (__attribute__((address_space(3))) void*)l, 16, 0, 0);
}

// ---------------------------------------------------------------------------
// fp32 -> bf16 converts (3 inputs + 4 weights), all coalesced.
// ---------------------------------------------------------------------------
struct ConvArgs { const float* src[7]; short* dst[7]; int n8[7]; };

__global__ __launch_bounds__(256) void convert_bf16(ConvArgs a) {
    const int y = blockIdx.y;
    const int t = blockIdx.x * 256 + threadIdx.x;
    if (t >= a.n8[y]) return;
    const float4* s = (const float4*)a.src[y];
    const float4 v0 = s[t * 2], v1 = s[t * 2 + 1];
    short8v o;
    o[0] = f2bf(v0.x); o[1] = f2bf(v0.y); o[2] = f2bf(v0.z); o[3] = f2bf(v0.w);
    o[4] = f2bf(v1.x); o[5] = f2bf(v1.y); o[6] = f2bf(v1.z); o[7] = f2bf(v1.w);
    *(short8v*)&a.dst[y][t * 8] = o;
}

// ---------------------------------------------------------------------------
// Mask int32 -> bf16 additive bias, fragment-tile layout
// idx = ((b*64+rt16)*64+c16)*256 + (col%16)*16 + (row%16).
// One wave per 16x16 tile; coalesced int4 row reads, in-register transpose.
// ---------------------------------------------------------------------------
__global__ __launch_bounds__(256) void convert_mask(
    const int* __restrict__ mask, short* __restrict__ dst)
{
    const int wave = threadIdx.x >> 6, lane = threadIdx.x & 63;
    const int tile = blockIdx.x * 4 + wave;          // (b*64+rt16)*64+c16
    const int bb   = tile >> 12;
    const int rt16 = (tile >> 6) & 63;
    const int c16  = tile & 63;
    const int row_in = lane >> 2;
    const int col4   = (lane & 3) * 4;
    const int4 mv = *(const int4*)&mask[((size_t)bb * T_SEQ + rt16 * 16 + row_in) * T_SEQ
                                        + c16 * 16 + col4];
    const short BB = f2bf(BIAS2);
    short* o = dst + (size_t)tile * 256 + row_in;
    o[(col4 + 0) * 16] = mv.x ? (short)0 : BB;
    o[(col4 + 1) * 16] = mv.y ? (short)0 : BB;
    o[(col4 + 2) * 16] = mv.z ? (short)0 : BB;
    o[(col4 + 3) * 16] = mv.w ? (short)0 : BB;
}

// ---------------------------------------------------------------------------
// bf16 MFMA GEMM core (m97 structure): C = (A(MxK) @ W(NxK)^T + bias) * scale
// MODE 0: fp32 C-order out  [m16][n16][rr][quad][lm]  (coalesced; LN-consumed)
// MODE 1: bf16 A-frag order [bh][t16][d8][t%16][8]    (flash lane-ordered)
// MODE 2: bf16 V^T frag out [bh][kt64][kh][dc][kq][dlm][8]
// ---------------------------------------------------------------------------
struct GemmB { const short* A; const short* W; const float* bias; short* out; float scale; };
struct QkvArgs { GemmB g[3]; };

template <int MODE>
__device__ inline void gemm_core(const short* __restrict__ A,
                                 const short* __restrict__ W,
                                 const float* __restrict__ bias,
                                 float scale,
                                 short* __restrict__ outS,
                                 float* __restrict__ outF,
                                 int m0, int n0)
{
    __shared__ short As[128 * 32];
    __shared__ short Bs[128 * 32];

    const int tid  = threadIdx.x;
    const int wave = tid >> 6;
    const int lane = tid & 63;
    const int quad = lane >> 4;
    const int lm   = lane & 15;
    const int wr   = wave >> 1;
    const int wc   = wave & 1;
    const int K    = EMB;

    const int G0 = wave * 64 + lane, G1 = G0 + 256;
    const short* aSrc0 = A + (size_t)(m0 + (G0 >> 2)) * K + (G0 & 3) * 8;
    const short* aSrc1 = A + (size_t)(m0 + (G1 >> 2)) * K + (G1 & 3) * 8;
    const short* bSrc0 = W + (size_t)(n0 + (G0 >> 2)) * K + (G0 & 3) * 8;
    const short* bSrc1 = W + (size_t)(n0 + (G1 >> 2)) * K + (G1 & 3) * 8;
    short* aDst0 = As + wave * 512;
    short* aDst1 = As + 2048 + wave * 512;
    short* bDst0 = Bs + wave * 512;
    short* bDst1 = Bs + 2048 + wave * 512;

    f32x4 acc[4][4];
#pragma unroll
    for (int i = 0; i < 4; ++i)
#pragma unroll
        for (int j = 0; j < 4; ++j) acc[i][j] = (f32x4){0.f, 0.f, 0.f, 0.f};

    for (int kk = 0; kk < K; kk += 32) {
        __syncthreads();
        glds16(aSrc0 + kk, aDst0);
        glds16(aSrc1 + kk, aDst1);
        glds16(bSrc0 + kk, bDst0);
        glds16(bSrc1 + kk, bDst1);
        __syncthreads();

        frag8 aF[4], bF[4];
#pragma unroll
        for (int i = 0; i < 4; ++i)
            aF[i] = *(const frag8*)&As[(wr * 64 + i * 16 + lm) * 32 + quad * 8];
#pragma unroll
        for (int j = 0; j < 4; ++j)
            bF[j] = *(const frag8*)&Bs[(wc * 64 + j * 16 + lm) * 32 + quad * 8];
#pragma unroll
        for (int i = 0; i < 4; ++i)
#pragma unroll
            for (int j = 0; j < 4; ++j)
                acc[i][j] = __builtin_amdgcn_mfma_f32_16x16x32_bf16(
                    aF[i], bF[j], acc[i][j], 0, 0, 0);
    }

#pragma unroll
    for (int i = 0; i < 4; ++i)
#pragma unroll
        for (int j = 0; j < 4; ++j) {
            const int n = n0 + wc * 64 + j * 16 + lm;
            const float bv = bias[n];
#pragma unroll
            for (int rr = 0; rr < 4; ++rr) {
                const int m = m0 + wr * 64 + i * 16 + quad * 4 + rr;
                const float val = (acc[i][j][rr] + bv) * scale;
                if (MODE == 0) {
                    // fp32 C-order: [m16][n16][rr][quad][lm] — coalesced
                    outF[((size_t)(m >> 4) * 64 + (n >> 4)) * 256 +
                         rr * 64 + quad * 16 + lm] = val;
                } else {
                    const int bb = m >> 10, tt = m & 1023;
                    const int h = n >> 6,  d  = n & 63;
                    const size_t bh = (size_t)bb * NH + h;
                    if (MODE == 1) {
                        // A-frag order (flash loads lane-ordered dwordx4)
                        outS[((bh * 64 + (tt >> 4)) * 8 + (d >> 3)) * 128 +
                             (tt & 15) * 8 + (d & 7)] = f2bf(val);
                    } else {
                        // V^T B-frag order
                        outS[((((bh * 16 + (tt >> 6)) * 2 + ((tt >> 5) & 1)) * 4 +
                              (d >> 4)) * 4 + ((tt >> 3) & 3)) * 128 +
                             (d & 15) * 8 + (tt & 7)] = f2bf(val);
                    }
                }
            }
        }
}

// XCD-colocating swizzle: all 8 n-blocks of one (m,z) share an XCD slot.
__global__ __launch_bounds__(256) void gemm_qkv(QkvArgs args) {
    const int id = blockIdx.x + 8 * blockIdx.y + 256 * blockIdx.z;  // 0..767
    const int a  = id & 7;
    const int k2 = id >> 3;          // 0..95
    const int nb = k2 & 7;
    const int c  = k2 >> 3;          // 0..11
    const int pair = a * 12 + c;     // 0..95
    const int mb = pair & 31;
    const int zb = pair >> 5;        // 0..2
    const GemmB g = args.g[zb];
    if (zb < 2) gemm_core<1>(g.A, g.W, g.bias, g.scale, g.out, nullptr, mb * 128, nb * 128);
    else        gemm_core<2>(g.A, g.W, g.bias, g.scale, g.out, nullptr, mb * 128, nb * 128);
}

__global__ __launch_bounds__(256) void gemm_wo(const short* __restrict__ A,
                                               const short* __restrict__ W,
                                               const float* __restrict__ bias,
                                               float* __restrict__ out) {
    const int id = blockIdx.x + 8 * blockIdx.y;   // 0..255
    const int a  = id & 7;
    const int k2 = id >> 3;          // 0..31
    const int nb = k2 & 7;
    const int c  = k2 >> 3;          // 0..3
    const int mb = a * 4 + c;        // 0..31
    gemm_core<0>(A, W, bias, 1.0f, nullptr, out, mb * 128, nb * 128);
}

// ---------------------------------------------------------------------------
// Flash attention: fragment-resident K/V (lane-ordered coalesced loads),
// fixed-max log2-domain softmax, deferred l reduction.
// XCD-colocated 1D grid: xcd = id&7 serves one batch's 8 heads (all q-tiles)
// so the (b,q0) mask slabs and (b,h) K/V stay resident in that XCD's L2.
// ---------------------------------------------------------------------------
__global__ __launch_bounds__(256, 4) void flash_attn_mfma(
    const short* __restrict__ qf_, const short* __restrict__ kf_,
    const short* __restrict__ vf_, const short* __restrict__ mf_,
    short* __restrict__ out)
{
    __shared__ short Pl[4][2][16][72];   // per-wave, parity double-buffered

    const int tid  = threadIdx.x;
    const int wave = tid >> 6;
    const int lane = tid & 63;
    const int quad = lane >> 4;
    const int lm   = lane & 15;

    const int id  = blockIdx.x;          // 0..1023
    const int xcd = id & 7;
    const int idx = id >> 3;             // 0..127
    const int bh_i = xcd * 8 + (idx >> 4);   // 0..63
    const int b  = bh_i >> 4, h = bh_i & 15;
    const int q0 = (idx & 15) * BQ;
    const size_t bh = (size_t)bh_i;

    // Q fragments (lane-ordered coalesced 1KB wave loads)
    const short* qb_ = qf_ + (bh * 64 + (q0 >> 4) + wave) * 1024;
    const frag8 qfa = *(const frag8*)&qb_[(quad * 16 + lm) * 8];
    const frag8 qfb = *(const frag8*)&qb_[((quad + 4) * 16 + lm) * 8];

    // mask fragment base for this wave's 16 q-rows
    const short* mrow = mf_ + ((size_t)b * 64 + (q0 >> 4) + wave) * (64 * 256)
                        + lm * 16 + quad * 4;

    f32x4 of[4];
#pragma unroll
    for (int dc = 0; dc < 4; ++dc) of[dc] = (f32x4){0.f, 0.f, 0.f, 0.f};
    float lsum[4] = {0.f, 0.f, 0.f, 0.f};

    for (int kt2 = 0; kt2 < T_SEQ / BK; ++kt2) {
        const int pp = kt2 & 1;

        // V fragments: 8 coalesced dwordx4
        frag8 vf[2][4];
        const short* vbase = vf_ + (bh * 16 + kt2) * 4096;
#pragma unroll
        for (int kh2 = 0; kh2 < 2; ++kh2)
#pragma unroll
            for (int dc = 0; dc < 4; ++dc)
                vf[kh2][dc] = *(const frag8*)
                    &vbase[((kh2 * 4 + dc) * 4 + quad) * 128 + lm * 8];

        // mask bias: 4 coalesced dwordx2
        short4v mb[4];
#pragma unroll
        for (int kc = 0; kc < 4; ++kc)
            mb[kc] = *(const short4v*)&mrow[(kt2 * 4 + kc) * 256];

        // S = Q'K^T + maskbias (acc-init); K frags lane-ordered dwordx4
        f32x4 s[4];
#pragma unroll
        for (int kc = 0; kc < 4; ++kc) {
            const short* kbase = kf_ + (bh * 64 + kt2 * 4 + kc) * 1024;
            const frag8 kfa = *(const frag8*)&kbase[(quad * 16 + lm) * 8];
            const frag8 kfb = *(const frag8*)&kbase[((quad + 4) * 16 + lm) * 8];
            f32x4 a = (f32x4){ bf2f((unsigned short)mb[kc][0]),
                               bf2f((unsigned short)mb[kc][1]),
                               bf2f((unsigned short)mb[kc][2]),
                               bf2f((unsigned short)mb[kc][3]) };
            a = __builtin_amdgcn_mfma_f32_16x16x32_bf16(qfa, kfa, a, 0, 0, 0);
            a = __builtin_amdgcn_mfma_f32_16x16x32_bf16(qfb, kfb, a, 0, 0, 0);
            s[kc] = a;
        }

        // fixed-max softmax: p = exp2(s); deferred row-sum
#pragma unroll
        for (int kc = 0; kc < 4; ++kc)
#pragma unroll
            for (int r = 0; r < 4; ++r) {
                const float p = exp2f(s[kc][r]);
                lsum[r] += p;
                Pl[wave][pp][quad * 4 + r][kc * 16 + lm] = f2bf_rhu(p);
            }

        // P fragments (C->A layout via per-wave LDS) + PV
        const frag8 pfa = *(const frag8*)&Pl[wave][pp][lm][quad * 8];
        const frag8 pfb = *(const frag8*)&Pl[wave][pp][lm][32 + quad * 8];
#pragma unroll
        for (int dc = 0; dc < 4; ++dc) {
            of[dc] = __builtin_amdgcn_mfma_f32_16x16x32_bf16(pfa, vf[0][dc], of[dc], 0, 0, 0);
            of[dc] = __builtin_amdgcn_mfma_f32_16x16x32_bf16(pfb, vf[1][dc], of[dc], 0, 0, 0);
        }
    }

    // final l reduction over the 16-lane lm group
#pragma unroll
    for (int r = 0; r < 4; ++r) {
        lsum[r] += __shfl_xor(lsum[r], 1);
        lsum[r] += __shfl_xor(lsum[r], 2);
        lsum[r] += __shfl_xor(lsum[r], 4);
        lsum[r] += __shfl_xor(lsum[r], 8);
    }
    float inv[4];
#pragma unroll
    for (int r = 0; r < 4; ++r) inv[r] = 1.0f / lsum[r];

    short* ob = out + ((size_t)b * T_SEQ + q0 + wave * 16) * EMB + h * HD;
#pragma unroll
    for (int dc = 0; dc < 4; ++dc)
#pragma unroll
        for (int r = 0; r < 4; ++r)
            ob[(size_t)(quad * 4 + r) * EMB + dc * 16 + lm] = f2bf(of[dc][r] * inv[r]);
}

// ---------------------------------------------------------------------------
// LayerNorm over last dim (1024); input in fp32 C-order, output row-major.
// ---------------------------------------------------------------------------
__global__ __launch_bounds__(256) void layernorm_k(
    const float* __restrict__ x, const float* __restrict__ gamma,
    const float* __restrict__ beta, float* __restrict__ out)
{
    __shared__ float ws1[4], ws2[4];
    const int tid = threadIdx.x;
    const int row = blockIdx.x;
    const int m16 = row >> 4, rr = row & 3, qd = (row >> 2) & 3;

    const float4 v = *(const float4*)&x[((size_t)m16 * 64 + (tid >> 2)) * 256 +
                                        rr * 64 + qd * 16 + (tid & 3) * 4];
    float s  = v.x + v.y + v.z + v.w;
    float ss = v.x * v.x + v.y * v.y + v.z * v.z + v.w * v.w;
#pragma unroll
    for (int off = 32; off > 0; off >>= 1) {
        s  += __shfl_down(s, off);
        ss += __shfl_down(ss, off);
    }
    if ((tid & 63) == 0) { ws1[tid >> 6] = s; ws2[tid >> 6] = ss; }
    __syncthreads();
    if (tid == 0) {
        const float a = ws1[0] + ws1[1] + ws1[2] + ws1[3];
        const float bsum = ws2[0] + ws2[1] + ws2[2] + ws2[3];
        const float mu = a * (1.0f / EMB);
        const float var = bsum * (1.0f / EMB) - mu * mu;
        ws1[0] = mu;
        ws2[0] = rsqrtf(var + 1e-5f);
    }
    __syncthreads();
    const float mu = ws1[0], rstd = ws2[0];

    const float4 g = *(const float4*)&gamma[tid * 4];
    const float4 bt = *(const float4*)&beta[tid * 4];
    float4 r;
    r.x = (v.x - mu) * rstd * g.x + bt.x;
    r.y = (v.y - mu) * rstd * g.y + bt.y;
    r.z = (v.z - mu) * rstd * g.z + bt.z;
    r.w = (v.w - mu) * rstd * g.w + bt.w;
    *(float4*)&out[(size_t)row * EMB + tid * 4] = r;
}

// ---------------------------------------------------------------------------
extern "C" void kernel_launch(void* const* d_in, const int* in_sizes, int n_in,
                              void* d_out, int out_size, void* d_ws, size_t ws_size,
                              hipStream_t stream) {
    const float* query = (const float*)d_in[0];
    const float* key_i = (const float*)d_in[1];
    const float* value = (const float*)d_in[2];
    const int*   mask  = (const int*)d_in[3];
    const float* Wq = (const float*)d_in[4];
    const float* bq = (const float*)d_in[5];
    const float* Wk = (const float*)d_in[6];
    const float* bk = (const float*)d_in[7];
    const float* Wv = (const float*)d_in[8];
    const float* bv = (const float*)d_in[9];
    const float* Wo = (const float*)d_in[10];
    const float* bo = (const float*)d_in[11];
    const float* gamma = (const float*)d_in[12];
    const float* beta  = (const float*)d_in[13];

    const size_t SZ = (size_t)NB * T_SEQ * EMB;   // 4.19M elements
    const size_t WZ = (size_t)EMB * EMB;          // 1.05M elements
    short* sws = (short*)d_ws;
    short* q_bf  = sws;               // dead after gemm_qkv; attnb overlays
    short* k_bf  = sws + SZ;          // dead after gemm_qkv; projb overlays
    short* v_bf  = sws + 2 * SZ;
    short* w_bf  = sws + 3 * SZ;      // Wq,Wk,Wv,Wo bf16
    short* qh    = sws + 4 * SZ;      // Q A-frag layout
    short* kh    = sws + 5 * SZ;      // K A-frag layout
    short* vh    = sws + 6 * SZ;      // V^T frag layout
    short* maskb = sws + 7 * SZ;      // bf16 bias, fragment tiles
    short* attnb = q_bf;
    float* projb = (float*)(sws + SZ);

    // 1a. bulk converts (inputs + weights)
    ConvArgs ca;
    ca.src[0] = query; ca.dst[0] = q_bf;          ca.n8[0] = (int)(SZ / 8);
    ca.src[1] = key_i; ca.dst[1] = k_bf;          ca.n8[1] = (int)(SZ / 8);
    ca.src[2] = value; ca.dst[2] = v_bf;          ca.n8[2] = (int)(SZ / 8);
    ca.src[3] = Wq;    ca.dst[3] = w_bf;          ca.n8[3] = (int)(WZ / 8);
    ca.src[4] = Wk;    ca.dst[4] = w_bf + WZ;     ca.n8[4] = (int)(WZ / 8);
    ca.src[5] = Wv;    ca.dst[5] = w_bf + 2 * WZ; ca.n8[5] = (int)(WZ / 8);
    ca.src[6] = Wo;    ca.dst[6] = w_bf + 3 * WZ; ca.n8[6] = (int)(WZ / 8);
    convert_bf16<<<dim3((SZ / 8 + 255) / 256, 7), 256, 0, stream>>>(ca);

    // 1b. mask -> frag-tile bias (coalesced)
    convert_mask<<<dim3(NB * 64 * 64 / 4), 256, 0, stream>>>(mask, maskb);

    // 2. QKV projections; Q pre-scaled by 0.125*log2e; frag-layout outputs
    QkvArgs qa;
    qa.g[0] = { q_bf, w_bf,          bq, qh, QSCALE };
    qa.g[1] = { k_bf, w_bf + WZ,     bk, kh, 1.0f };
    qa.g[2] = { v_bf, w_bf + 2 * WZ, bv, vh, 1.0f };
    gemm_qkv<<<dim3(EMB / 128, NB * T_SEQ / 128, 3), 256, 0, stream>>>(qa);

    // 3. flash attention (XCD-colocated 1D grid)
    flash_attn_mfma<<<dim3(T_SEQ / BQ * NH * NB), 256, 0, stream>>>(qh, kh, vh, maskb, attnb);

    // 4. output projection (fp32 C-order out)
    gemm_wo<<<dim3(EMB / 128, NB * T_SEQ / 128), 256, 0, stream>>>(
        attnb, w_bf + 3 * WZ, bo, projb);

    // 5. layernorm (reads C-order, writes row-major)
    layernorm_k<<<dim3(NB * T_SEQ), 256, 0, stream>>>(projb, gamma, beta, (float*)d_out);
}

// Round 8
// 258.706 us; speedup vs baseline: 1.1733x; 1.0303x over previous
//
#include <hip/hip_runtime.h>
#include <cmath>

#define T_SEQ 1024
#define EMB   1024
#define NH    16
#define HD    64
#define NB    4
#define BQ    64
#define BK    64

// softmax computed in log2 domain: exp(x) == exp2(x * log2e)
#define QSCALE 0.18033688011112042f   /* 0.125 * log2(e) */
#define BIAS2  -1.44269504e9f         /* -1e9 * log2(e) */

using frag8   = __attribute__((ext_vector_type(8))) short;
using f32x4   = __attribute__((ext_vector_type(4))) float;
using short4v = __attribute__((ext_vector_type(4))) short;
using short8v = __attribute__((ext_vector_type(8))) short;

__device__ inline short f2bf(float f) {               // RNE
    union { float f; unsigned u; } x; x.f = f;
    unsigned r = (x.u + 0x7FFFu + ((x.u >> 16) & 1u)) >> 16;
    return (short)r;
}
__device__ inline short f2bf_rhu(float f) {           // round-half-up, 2 ops
    union { float f; unsigned u; } x; x.f = f;
    return (short)((x.u + 0x8000u) >> 16);
}
__device__ inline float bf2f(unsigned short u) {
    union { unsigned u; float f; } x; x.u = ((unsigned)u) << 16;
    return x.f;
}

__device__ inline void glds16(const short* g, short* l) {
    __builtin_amdgcn_global_load_lds(
        (const __attribute__((address_space(1))) void*)g,
        (__attribute__((address_space(3))) void*)l, 16, 0, 0);
}

// ---------------------------------------------------------------------------
// fp32 -> bf16 converts (3 inputs + 4 weights), all coalesced.
// ---------------------------------------------------------------------------
struct ConvArgs { const float* src[7]; short* dst[7]; int n8[7]; };

__global__ __launch_bounds__(256) void convert_bf16(ConvArgs a) {
    const int y = blockIdx.y;
    const int t = blockIdx.x * 256 + threadIdx.x;
    if (t >= a.n8[y]) return;
    const float4* s = (const float4*)a.src[y];
    const float4 v0 = s[t * 2], v1 = s[t * 2 + 1];
    short8v o;
    o[0] = f2bf(v0.x); o[1] = f2bf(v0.y); o[2] = f2bf(v0.z); o[3] = f2bf(v0.w);
    o[4] = f2bf(v1.x); o[5] = f2bf(v1.y); o[6] = f2bf(v1.z); o[7] = f2bf(v1.w);
    *(short8v*)&a.dst[y][t * 8] = o;
}

// ---------------------------------------------------------------------------
// Mask int32 -> bf16 additive bias, TRANSPOSED fragment-tile layout
// idx = ((b*64+q16)*64+k16)*256 + (q%16)*16 + (key%16)   [S^T orientation]
// One wave per 16x16 tile; coalesced int4 reads, contiguous short4 writes.
// ---------------------------------------------------------------------------
__global__ __launch_bounds__(256) void convert_mask(
    const int* __restrict__ mask, short* __restrict__ dst)
{
    const int wave = threadIdx.x >> 6, lane = threadIdx.x & 63;
    const int tile = blockIdx.x * 4 + wave;          // (b*64+q16)*64+k16
    const int bb   = tile >> 12;
    const int q16  = (tile >> 6) & 63;
    const int k16  = tile & 63;
    const int qrow = lane >> 2;                      // q row within tile
    const int col4 = (lane & 3) * 4;                 // key cols
    const int4 mv = *(const int4*)&mask[((size_t)bb * T_SEQ + q16 * 16 + qrow) * T_SEQ
                                        + k16 * 16 + col4];
    const short BB = f2bf(BIAS2);
    short4v o;
    o[0] = mv.x ? (short)0 : BB;
    o[1] = mv.y ? (short)0 : BB;
    o[2] = mv.z ? (short)0 : BB;
    o[3] = mv.w ? (short)0 : BB;
    *(short4v*)&dst[(size_t)tile * 256 + qrow * 16 + col4] = o;
}

// ---------------------------------------------------------------------------
// bf16 MFMA GEMM core: C = (A(MxK) @ W(NxK)^T + bias) * scale
// BK=64 as TWO BK=32 panels per barrier pair (32 MFMAs per barrier pair;
// each panel keeps the proven 128x32 m97 LDS bank layout).
// MODE 0: fp32 C-order out  [m16][n16][rr][quad][lm]  (coalesced; LN-consumed)
// MODE 1: bf16 A-frag order [bh][t16][d8][t%16][8]    (flash lane-ordered)
// MODE 2: bf16 V^T frag out [bh][kt64][kh][dc][kq][dlm][8]
// ---------------------------------------------------------------------------
struct GemmB { const short* A; const short* W; const float* bias; short* out; float scale; };
struct QkvArgs { GemmB g[3]; };

template <int MODE>
__device__ inline void gemm_core(const short* __restrict__ A,
                                 const short* __restrict__ W,
                                 const float* __restrict__ bias,
                                 float scale,
                                 short* __restrict__ outS,
                                 float* __restrict__ outF,
                                 int m0, int n0)
{
    __shared__ short As[2][128 * 32];
    __shared__ short Bs[2][128 * 32];

    const int tid  = threadIdx.x;
    const int wave = tid >> 6;
    const int lane = tid & 63;
    const int quad = lane >> 4;
    const int lm   = lane & 15;
    const int wr   = wave >> 1;
    const int wc   = wave & 1;
    const int K    = EMB;

    const int G0 = wave * 64 + lane, G1 = G0 + 256;
    const short* aSrc0 = A + (size_t)(m0 + (G0 >> 2)) * K + (G0 & 3) * 8;
    const short* aSrc1 = A + (size_t)(m0 + (G1 >> 2)) * K + (G1 & 3) * 8;
    const short* bSrc0 = W + (size_t)(n0 + (G0 >> 2)) * K + (G0 & 3) * 8;
    const short* bSrc1 = W + (size_t)(n0 + (G1 >> 2)) * K + (G1 & 3) * 8;
    short* aDst0 = &As[0][wave * 512];
    short* aDst1 = &As[0][2048 + wave * 512];
    short* bDst0 = &Bs[0][wave * 512];
    short* bDst1 = &Bs[0][2048 + wave * 512];

    f32x4 acc[4][4];
#pragma unroll
    for (int i = 0; i < 4; ++i)
#pragma unroll
        for (int j = 0; j < 4; ++j) acc[i][j] = (f32x4){0.f, 0.f, 0.f, 0.f};

    for (int kk = 0; kk < K; kk += 64) {
        __syncthreads();
        glds16(aSrc0 + kk,      aDst0);
        glds16(aSrc1 + kk,      aDst1);
        glds16(bSrc0 + kk,      bDst0);
        glds16(bSrc1 + kk,      bDst1);
        glds16(aSrc0 + kk + 32, aDst0 + 4096);
        glds16(aSrc1 + kk + 32, aDst1 + 4096);
        glds16(bSrc0 + kk + 32, bDst0 + 4096);
        glds16(bSrc1 + kk + 32, bDst1 + 4096);
        __syncthreads();

#pragma unroll
        for (int p = 0; p < 2; ++p) {
            frag8 aF[4], bF[4];
#pragma unroll
            for (int i = 0; i < 4; ++i)
                aF[i] = *(const frag8*)&As[p][(wr * 64 + i * 16 + lm) * 32 + quad * 8];
#pragma unroll
            for (int j = 0; j < 4; ++j)
                bF[j] = *(const frag8*)&Bs[p][(wc * 64 + j * 16 + lm) * 32 + quad * 8];
#pragma unroll
            for (int i = 0; i < 4; ++i)
#pragma unroll
                for (int j = 0; j < 4; ++j)
                    acc[i][j] = __builtin_amdgcn_mfma_f32_16x16x32_bf16(
                        aF[i], bF[j], acc[i][j], 0, 0, 0);
        }
    }

#pragma unroll
    for (int i = 0; i < 4; ++i)
#pragma unroll
        for (int j = 0; j < 4; ++j) {
            const int n = n0 + wc * 64 + j * 16 + lm;
            const float bv = bias[n];
#pragma unroll
            for (int rr = 0; rr < 4; ++rr) {
                const int m = m0 + wr * 64 + i * 16 + quad * 4 + rr;
                const float val = (acc[i][j][rr] + bv) * scale;
                if (MODE == 0) {
                    outF[((size_t)(m >> 4) * 64 + (n >> 4)) * 256 +
                         rr * 64 + quad * 16 + lm] = val;
                } else {
                    const int bb = m >> 10, tt = m & 1023;
                    const int h = n >> 6,  d  = n & 63;
                    const size_t bh = (size_t)bb * NH + h;
                    if (MODE == 1) {
                        outS[((bh * 64 + (tt >> 4)) * 8 + (d >> 3)) * 128 +
                             (tt & 15) * 8 + (d & 7)] = f2bf(val);
                    } else {
                        outS[((((bh * 16 + (tt >> 6)) * 2 + ((tt >> 5) & 1)) * 4 +
                              (d >> 4)) * 4 + ((tt >> 3) & 3)) * 128 +
                             (d & 15) * 8 + (tt & 7)] = f2bf(val);
                    }
                }
            }
        }
}

// XCD-colocating swizzle: all 8 n-blocks of one (m,z) share an XCD slot.
__global__ __launch_bounds__(256, 3) void gemm_qkv(QkvArgs args) {
    const int id = blockIdx.x + 8 * blockIdx.y + 256 * blockIdx.z;  // 0..767
    const int a  = id & 7;
    const int k2 = id >> 3;          // 0..95
    const int nb = k2 & 7;
    const int c  = k2 >> 3;          // 0..11
    const int pair = a * 12 + c;     // 0..95
    const int mb = pair & 31;
    const int zb = pair >> 5;        // 0..2
    const GemmB g = args.g[zb];
    if (zb < 2) gemm_core<1>(g.A, g.W, g.bias, g.scale, g.out, nullptr, mb * 128, nb * 128);
    else        gemm_core<2>(g.A, g.W, g.bias, g.scale, g.out, nullptr, mb * 128, nb * 128);
}

__global__ __launch_bounds__(256, 3) void gemm_wo(const short* __restrict__ A,
                                                  const short* __restrict__ W,
                                                  const float* __restrict__ bias,
                                                  float* __restrict__ out) {
    const int id = blockIdx.x + 8 * blockIdx.y;   // 0..255
    const int a  = id & 7;
    const int k2 = id >> 3;          // 0..31
    const int nb = k2 & 7;
    const int c  = k2 >> 3;          // 0..3
    const int mb = a * 4 + c;        // 0..31
    gemm_core<0>(A, W, bias, 1.0f, nullptr, out, mb * 128, nb * 128);
}

// ---------------------------------------------------------------------------
// Flash attention, S^T form: S^T = MFMA(A=K, B=Q) so q lives on lm and keys
// on quad/regs. lsum is lane-local (2 shuffles at the end). P^T stores to LDS
// as b64; PV uses V^T frags as the A operand; O^T packs to b64 stores.
// XCD-colocated 1D grid (xcd = id&7 owns one batch's 8 heads).
// ---------------------------------------------------------------------------
__global__ __launch_bounds__(256, 4) void flash_attn_mfma(
    const short* __restrict__ qf_, const short* __restrict__ kf_,
    const short* __restrict__ vf_, const short* __restrict__ mf_,
    short* __restrict__ out)
{
    __shared__ short Pl[4][2][16][72];   // per-wave, parity double-buffered

    const int tid  = threadIdx.x;
    const int wave = tid >> 6;
    const int lane = tid & 63;
    const int quad = lane >> 4;
    const int lm   = lane & 15;

    const int id  = blockIdx.x;          // 0..1023
    const int xcd = id & 7;
    const int idx = id >> 3;             // 0..127
    const int bh_i = xcd * 8 + (idx >> 4);   // 0..63
    const int b  = bh_i >> 4, h = bh_i & 15;
    const int q0 = (idx & 15) * BQ;
    const size_t bh = (size_t)bh_i;

    // Q fragments (lane-ordered coalesced 1KB wave loads) — used as B operand
    const short* qb_ = qf_ + (bh * 64 + (q0 >> 4) + wave) * 1024;
    const frag8 qfa = *(const frag8*)&qb_[(quad * 16 + lm) * 8];
    const frag8 qfb = *(const frag8*)&qb_[((quad + 4) * 16 + lm) * 8];

    // transposed mask tiles: [q%16][key%16]; this lane: q=lm, keys=quad*4..+3
    const short* mrow = mf_ + ((size_t)b * 64 + (q0 >> 4) + wave) * (64 * 256)
                        + lm * 16 + quad * 4;

    f32x4 of[4];
#pragma unroll
    for (int dc = 0; dc < 4; ++dc) of[dc] = (f32x4){0.f, 0.f, 0.f, 0.f};
    float lsum = 0.f;

    for (int kt2 = 0; kt2 < T_SEQ / BK; ++kt2) {
        const int pp = kt2 & 1;

        // V^T fragments (A-operand): 8 coalesced dwordx4
        frag8 vf[2][4];
        const short* vbase = vf_ + (bh * 16 + kt2) * 4096;
#pragma unroll
        for (int kh2 = 0; kh2 < 2; ++kh2)
#pragma unroll
            for (int dc = 0; dc < 4; ++dc)
                vf[kh2][dc] = *(const frag8*)
                    &vbase[((kh2 * 4 + dc) * 4 + quad) * 128 + lm * 8];

        // mask bias: 4 b64 loads (keys quad*4..+3 at q=lm)
        short4v mb[4];
#pragma unroll
        for (int kc = 0; kc < 4; ++kc)
            mb[kc] = *(const short4v*)&mrow[(kt2 * 4 + kc) * 256];

        // S^T = K Q^T + maskbias (acc-init): rows=keys, cols=q
        f32x4 s[4];
#pragma unroll
        for (int kc = 0; kc < 4; ++kc) {
            const short* kbase = kf_ + (bh * 64 + kt2 * 4 + kc) * 1024;
            const frag8 kfa = *(const frag8*)&kbase[(quad * 16 + lm) * 8];
            const frag8 kfb = *(const frag8*)&kbase[((quad + 4) * 16 + lm) * 8];
            f32x4 a = (f32x4){ bf2f((unsigned short)mb[kc][0]),
                               bf2f((unsigned short)mb[kc][1]),
                               bf2f((unsigned short)mb[kc][2]),
                               bf2f((unsigned short)mb[kc][3]) };
            a = __builtin_amdgcn_mfma_f32_16x16x32_bf16(kfa, qfa, a, 0, 0, 0);
            a = __builtin_amdgcn_mfma_f32_16x16x32_bf16(kfb, qfb, a, 0, 0, 0);
            s[kc] = a;
        }

        // fixed-max softmax: p = exp2(s^T); lane-local row-sum (q = lm)
#pragma unroll
        for (int kc = 0; kc < 4; ++kc) {
            float p0 = exp2f(s[kc][0]), p1 = exp2f(s[kc][1]);
            float p2 = exp2f(s[kc][2]), p3 = exp2f(s[kc][3]);
            lsum += (p0 + p1) + (p2 + p3);
            short4v pk;
            pk[0] = f2bf_rhu(p0); pk[1] = f2bf_rhu(p1);
            pk[2] = f2bf_rhu(p2); pk[3] = f2bf_rhu(p3);
            // P^T[q=lm][key=kc*16+quad*4 .. +3] — one b64 write
            *(short4v*)&Pl[wave][pp][lm][kc * 16 + quad * 4] = pk;
        }

        // P^T fragments (B-operand): [n=q=lm][k=key]
        const frag8 pfa = *(const frag8*)&Pl[wave][pp][lm][quad * 8];
        const frag8 pfb = *(const frag8*)&Pl[wave][pp][lm][32 + quad * 8];
#pragma unroll
        for (int dc = 0; dc < 4; ++dc) {
            of[dc] = __builtin_amdgcn_mfma_f32_16x16x32_bf16(vf[0][dc], pfa, of[dc], 0, 0, 0);
            of[dc] = __builtin_amdgcn_mfma_f32_16x16x32_bf16(vf[1][dc], pfb, of[dc], 0, 0, 0);
        }
    }

    // final l reduction across quads (q = lm fixed per lane)
    lsum += __shfl_xor(lsum, 16);
    lsum += __shfl_xor(lsum, 32);
    const float inv = 1.0f / lsum;

    // O^T C-layout: row = d = dc*16 + quad*4 + rr, col = q = lm.
    // 4 consecutive d per (dc) -> one b64 store.
    short* ob = out + ((size_t)b * T_SEQ + q0 + wave * 16 + lm) * EMB + h * HD;
#pragma unroll
    for (int dc = 0; dc < 4; ++dc) {
        short4v o4;
#pragma unroll
        for (int rr = 0; rr < 4; ++rr) o4[rr] = f2bf(of[dc][rr] * inv);
        *(short4v*)&ob[dc * 16 + quad * 4] = o4;
    }
}

// ---------------------------------------------------------------------------
// LayerNorm over last dim (1024); input in fp32 C-order, output row-major.
// ---------------------------------------------------------------------------
__global__ __launch_bounds__(256) void layernorm_k(
    const float* __restrict__ x, const float* __restrict__ gamma,
    const float* __restrict__ beta, float* __restrict__ out)
{
    __shared__ float ws1[4], ws2[4];
    const int tid = threadIdx.x;
    const int row = blockIdx.x;
    const int m16 = row >> 4, rr = row & 3, qd = (row >> 2) & 3;

    const float4 v = *(const float4*)&x[((size_t)m16 * 64 + (tid >> 2)) * 256 +
                                        rr * 64 + qd * 16 + (tid & 3) * 4];
    float s  = v.x + v.y + v.z + v.w;
    float ss = v.x * v.x + v.y * v.y + v.z * v.z + v.w * v.w;
#pragma unroll
    for (int off = 32; off > 0; off >>= 1) {
        s  += __shfl_down(s, off);
        ss += __shfl_down(ss, off);
    }
    if ((tid & 63) == 0) { ws1[tid >> 6] = s; ws2[tid >> 6] = ss; }
    __syncthreads();
    if (tid == 0) {
        const float a = ws1[0] + ws1[1] + ws1[2] + ws1[3];
        const float bsum = ws2[0] + ws2[1] + ws2[2] + ws2[3];
        const float mu = a * (1.0f / EMB);
        const float var = bsum * (1.0f / EMB) - mu * mu;
        ws1[0] = mu;
        ws2[0] = rsqrtf(var + 1e-5f);
    }
    __syncthreads();
    const float mu = ws1[0], rstd = ws2[0];

    const float4 g = *(const float4*)&gamma[tid * 4];
    const float4 bt = *(const float4*)&beta[tid * 4];
    float4 r;
    r.x = (v.x - mu) * rstd * g.x + bt.x;
    r.y = (v.y - mu) * rstd * g.y + bt.y;
    r.z = (v.z - mu) * rstd * g.z + bt.z;
    r.w = (v.w - mu) * rstd * g.w + bt.w;
    *(float4*)&out[(size_t)row * EMB + tid * 4] = r;
}

// ---------------------------------------------------------------------------
extern "C" void kernel_launch(void* const* d_in, const int* in_sizes, int n_in,
                              void* d_out, int out_size, void* d_ws, size_t ws_size,
                              hipStream_t stream) {
    const float* query = (const float*)d_in[0];
    const float* key_i = (const float*)d_in[1];
    const float* value = (const float*)d_in[2];
    const int*   mask  = (const int*)d_in[3];
    const float* Wq = (const float*)d_in[4];
    const float* bq = (const float*)d_in[5];
    const float* Wk = (const float*)d_in[6];
    const float* bk = (const float*)d_in[7];
    const float* Wv = (const float*)d_in[8];
    const float* bv = (const float*)d_in[9];
    const float* Wo = (const float*)d_in[10];
    const float* bo = (const float*)d_in[11];
    const float* gamma = (const float*)d_in[12];
    const float* beta  = (const float*)d_in[13];

    const size_t SZ = (size_t)NB * T_SEQ * EMB;   // 4.19M elements
    const size_t WZ = (size_t)EMB * EMB;          // 1.05M elements
    short* sws = (short*)d_ws;
    short* q_bf  = sws;               // dead after gemm_qkv; attnb overlays
    short* k_bf  = sws + SZ;          // dead after gemm_qkv; projb overlays
    short* v_bf  = sws + 2 * SZ;
    short* w_bf  = sws + 3 * SZ;      // Wq,Wk,Wv,Wo bf16
    short* qh    = sws + 4 * SZ;      // Q A-frag layout
    short* kh    = sws + 5 * SZ;      // K A-frag layout
    short* vh    = sws + 6 * SZ;      // V^T frag layout
    short* maskb = sws + 7 * SZ;      // bf16 bias, transposed frag tiles
    short* attnb = q_bf;
    float* projb = (float*)(sws + SZ);

    // 1a. bulk converts (inputs + weights)
    ConvArgs ca;
    ca.src[0] = query; ca.dst[0] = q_bf;          ca.n8[0] = (int)(SZ / 8);
    ca.src[1] = key_i; ca.dst[1] = k_bf;          ca.n8[1] = (int)(SZ / 8);
    ca.src[2] = value; ca.dst[2] = v_bf;          ca.n8[2] = (int)(SZ / 8);
    ca.src[3] = Wq;    ca.dst[3] = w_bf;          ca.n8[3] = (int)(WZ / 8);
    ca.src[4] = Wk;    ca.dst[4] = w_bf + WZ;     ca.n8[4] = (int)(WZ / 8);
    ca.src[5] = Wv;    ca.dst[5] = w_bf + 2 * WZ; ca.n8[5] = (int)(WZ / 8);
    ca.src[6] = Wo;    ca.dst[6] = w_bf + 3 * WZ; ca.n8[6] = (int)(WZ / 8);
    convert_bf16<<<dim3((SZ / 8 + 255) / 256, 7), 256, 0, stream>>>(ca);

    // 1b. mask -> transposed frag-tile bias (coalesced both sides)
    convert_mask<<<dim3(NB * 64 * 64 / 4), 256, 0, stream>>>(mask, maskb);

    // 2. QKV projections; Q pre-scaled by 0.125*log2e; frag-layout outputs
    QkvArgs qa;
    qa.g[0] = { q_bf, w_bf,          bq, qh, QSCALE };
    qa.g[1] = { k_bf, w_bf + WZ,     bk, kh, 1.0f };
    qa.g[2] = { v_bf, w_bf + 2 * WZ, bv, vh, 1.0f };
    gemm_qkv<<<dim3(EMB / 128, NB * T_SEQ / 128, 3), 256, 0, stream>>>(qa);

    // 3. flash attention (S^T form, XCD-colocated 1D grid)
    flash_attn_mfma<<<dim3(T_SEQ / BQ * NH * NB), 256, 0, stream>>>(qh, kh, vh, maskb, attnb);

    // 4. output projection (fp32 C-order out)
    gemm_wo<<<dim3(EMB / 128, NB * T_SEQ / 128), 256, 0, stream>>>(
        attnb, w_bf + 3 * WZ, bo, projb);

    // 5. layernorm (reads C-order, writes row-major)
    layernorm_k<<<dim3(NB * T_SEQ), 256, 0, stream>>>(projb, gamma, beta, (float*)d_out);
}